// Round 1
// baseline (344.606 us; speedup 1.0000x reference)
//
#include <hip/hip_runtime.h>
#include <hip/hip_bf16.h>

// Swin window MHSA, MI355X, round 7.
//   k_prep : Aext[2176x256]=G'(+w1/w2 rows), Wov3[256x2048], cvec, relL2(+c0)
//   k_conv : X fp32 -> rolled bf16 Xroll[n][3200][256]  (coalesced stores)
//   k_gemm1: M_T[t][a'] = Xroll . Aext^T  -- BK=256 single-barrier, DMA B-fill
//            R7: XCD-bijective swizzle (XCD k owns n=k), full A-slice register
//            prefetch before the barrier, nontemporal MT stores (bypass L2).
//   k_attn2: per (n,window): S=Xp.M, softmax, T=X.wmap; T overwrites M in-place
//   k_gemm3: out[o][t] = Wov3 . T_T^T + cvec  -- 128x128, BK=128, DMA fills
//            R7: XCD swizzle + nontemporal out stores.

#define NBATCH 8
#define MSTR   2176           // M_T / T_T row stride (a'-dim, 17 tiles of 128)
#define TROWS  3200           // padded token rows (25 tiles of 128)

typedef unsigned short ushort_t;
typedef __attribute__((ext_vector_type(8))) short bf16x8;   // 8 bf16 = 4 VGPR
typedef __attribute__((ext_vector_type(8))) unsigned short u16x8;
typedef __attribute__((ext_vector_type(4))) float f32x4;    // MFMA acc

__device__ __forceinline__ float b2f(ushort_t u) {
  union { unsigned int i; float f; } v; v.i = ((unsigned int)u) << 16; return v.f;
}
__device__ __forceinline__ ushort_t f2b(float f) {
  union { float f; unsigned int u; } v; v.f = f;
  unsigned int u = v.u;
  return (ushort_t)((u + 0x7FFFu + ((u >> 16) & 1u)) >> 16);
}
__device__ __forceinline__ int regof(int y) { return (y < 49) ? 0 : ((y < 53) ? 1 : 2); }
__device__ __forceinline__ int div7(int t) { return (t * 37) >> 8; }  // t/7, t<64
__device__ __forceinline__ int tmap(int p, int gi, int gj) {
  int wi = div7(p); return (gi * 7 + wi) * 56 + gj * 7 + (p - wi * 7);
}
__device__ __forceinline__ ushort4 pack4(f32x4 a) {
  ushort4 u; u.x = f2b(a[0]); u.y = f2b(a[1]); u.z = f2b(a[2]); u.w = f2b(a[3]);
  return u;
}
// async global->LDS, 16B per lane; lds dest must be wave-uniform base
__device__ __forceinline__ void gload_lds16(const ushort_t* g, ushort_t* l) {
  __builtin_amdgcn_global_load_lds(
      (const __attribute__((address_space(1))) void*)g,
      (__attribute__((address_space(3))) void*)l, 16, 0, 0);
}

// ================= prep (unchanged) =================
__global__ void k_prep(const float* __restrict__ Wk, const float* __restrict__ Wq,
                       const float* __restrict__ Wo, const float* __restrict__ Wv,
                       const float* __restrict__ bk, const float* __restrict__ bq,
                       const float* __restrict__ bv, const float* __restrict__ bo,
                       const float* __restrict__ relc,
                       ushort_t* __restrict__ Aext, ushort_t* __restrict__ Wov3,
                       float* __restrict__ cvec, float* __restrict__ relL2) {
  __shared__ float red[8];
  int blk = blockIdx.x, t = threadIdx.x;
  if (blk < 512) {
    int h = blk >> 6, b0 = (blk & 63) << 2, a = t;
    const float* wkh = Wk + h * 65536;
    const float* wqh = Wq + h * 65536;
    float a0 = 0.f, a1 = 0.f, a2 = 0.f, a3 = 0.f;
    for (int dd = 0; dd < 256; ++dd) {
      float wk = wkh[dd * 256 + a];
      float4 w4 = *(const float4*)(wqh + dd * 256 + b0);
      a0 += wk * w4.x; a1 += wk * w4.y; a2 += wk * w4.z; a3 += wk * w4.w;
    }
    ushort4 u; u.x = f2b(a0); u.y = f2b(a1); u.z = f2b(a2); u.w = f2b(a3);
    *(ushort4*)(Aext + (h * 256 + a) * 256 + b0) = u;
  } else if (blk < 1024) {
    int bb = blk - 512;
    int h = bb >> 6, o0 = (bb & 63) << 2, d = t;
    float a0 = 0.f, a1 = 0.f, a2 = 0.f, a3 = 0.f;
    for (int dd = 0; dd < 256; ++dd) {
      float wv = Wv[(h * 256 + dd) * 256 + d];
      a0 += Wo[(o0 + 0) * 2048 + h * 256 + dd] * wv;
      a1 += Wo[(o0 + 1) * 2048 + h * 256 + dd] * wv;
      a2 += Wo[(o0 + 2) * 2048 + h * 256 + dd] * wv;
      a3 += Wo[(o0 + 3) * 2048 + h * 256 + dd] * wv;
    }
    Wov3[(o0 + 0) * 2048 + h * 256 + d] = f2b(a0);
    Wov3[(o0 + 1) * 2048 + h * 256 + d] = f2b(a1);
    Wov3[(o0 + 2) * 2048 + h * 256 + d] = f2b(a2);
    Wov3[(o0 + 3) * 2048 + h * 256 + d] = f2b(a3);
  } else if (blk < 1032) {
    int h = blk - 1024;
    float s1 = 0.f, s2 = 0.f;
    for (int dd = 0; dd < 256; ++dd) {
      s1 += bk[h * 256 + dd] * Wq[(h * 256 + dd) * 256 + t];
      s2 += bq[h * 256 + dd] * Wk[(h * 256 + dd) * 256 + t];
    }
    Aext[(2048 + h) * 256 + t] = f2b(s1);
    Aext[(2056 + h) * 256 + t] = f2b(s2);
  } else if (blk == 1032) {
    for (int i = t; i < 112 * 256 / 8; i += 256)
      *(u16x8*)(Aext + 2064 * 256 + i * 8) = (u16x8){0,0,0,0,0,0,0,0};
  } else if (blk < 1289) {
    int o = blk - 1033;
    const float* wob = Wo + o * 2048;
    float acc = 0.f;
#pragma unroll
    for (int j = 0; j < 8; ++j) acc += wob[j * 256 + t] * bv[j * 256 + t];
#pragma unroll
    for (int s = 1; s < 64; s <<= 1) acc += __shfl_xor(acc, s);
    if ((t & 63) == 0) red[t >> 6] = acc;
    __syncthreads();
    if (t == 0) cvec[o] = bo[o] + red[0] + red[1] + red[2] + red[3];
  } else {
    if (t < 8) {
      float c = 0.f;
      for (int dd = 0; dd < 256; ++dd) c += bk[t * 256 + dd] * bq[t * 256 + dd];
      red[t] = c * 0.0625f;
    }
    __syncthreads();
    for (int i = t; i < 8 * 169; i += 256) {
      int h = i / 169, idx = i - h * 169;
      relL2[i] = relc[idx * 8 + h] + red[h];
    }
  }
}

// ================= conv: rolled gather, coalesced bf16 stores =============
__global__ void k_conv(const float* __restrict__ X, ushort_t* __restrict__ Xroll) {
  const int n = blockIdx.x / 57, y = blockIdx.x % 57;
  ushort_t* xr = Xroll + (size_t)n * TROWS * 256;
  const int d = threadIdx.x;
  if (y == 56) {  // zero pad rows 3136..3199
    for (int i = d; i < 64 * 256 / 8; i += 256)
      *(u16x8*)(xr + 3136 * 256 + i * 8) = (u16x8){0,0,0,0,0,0,0,0};
    return;
  }
  const int c = d >> 4, p1 = (d >> 2) & 3, p2 = d & 3;
  const int sp = c * 16 + (((p1 + 1) & 3) << 2) + ((p2 + 1) & 3);
  const int ty = (p1 == 3) ? y : ((y == 0) ? 55 : y - 1);
  const float* rowp = X + (size_t)n * 256 * 3136 + sp * 3136 + ty * 56;
  ushort_t* orow = xr + y * 56 * 256 + d;
  for (int x = 0; x < 56; ++x) {
    int tx = (p2 == 3) ? x : ((x == 0) ? 55 : x - 1);
    orow[x * 256] = f2b(rowp[tx]);   // 256 lanes -> 512B contiguous store
  }
}

// ================= gemm1: M_T[t][a'] = Xroll . Aext^T =====================
// BK=256 (full K): one DMA fill of B[128][256] (swizzled), ONE barrier.
// R7: (1) XCD-bijective block swizzle -- XCD k owns n=k, so the 17 aa-blocks
//     sharing an Xroll t-tile hit the SAME L2 (working set 1.6MB Xroll_n +
//     1.06MB Aext < 4MB); (2) the ENTIRE A-slice (32 bf16x8 = 128 VGPR) is
//     prefetched before the barrier so the MFMA loop has no global latency;
//     (3) MT stores are nontemporal: the 109MB write stream bypasses L2.
__global__ __launch_bounds__(256, 2) void k_gemm1(
    const ushort_t* __restrict__ Xroll, const ushort_t* __restrict__ Aext,
    ushort_t* __restrict__ MT) {
  __shared__ ushort_t Bsm[128 * 256];   // 64 KB
  const int bx0 = blockIdx.x;
  const int bx = (bx0 & 7) * 425 + (bx0 >> 3);   // bijective: 3400 = 8*425
  const int n = bx / 425, r = bx % 425;
  const int tt = r / 17, aa = r % 17;
  const int a0 = aa * 128, t0 = tt * 128;
  const int tid = threadIdx.x, wave = tid >> 6, lane = tid & 63;
  const int quad = lane >> 4, l16 = lane & 15;
  const int wa = wave >> 1, wt = wave & 1;
  const ushort_t* Xn = Xroll + (size_t)n * TROWS * 256;
  ushort_t* Mn = MT + (size_t)n * TROWS * MSTR;

  // fill: slot S holds 16B chunk (r=S>>5, c=(S&24)|((S^r)&7)) of row t0+r
#pragma unroll
  for (int i = 0; i < 16; ++i) {
    int S = i * 256 + tid;
    int rr = S >> 5, sc = S & 31;
    int c = (sc & 24) | ((sc ^ rr) & 7);
    gload_lds16(Xn + (t0 + rr) * 256 + c * 8, &Bsm[(i * 256 + wave * 64) * 8]);
  }

  // full A-slice prefetch: issued while the DMA fill is in flight; the
  // barrier's vmcnt(0) drain covers both. 8 kk x 4 frags = 128 VGPR.
  const ushort_t* abase = Aext + (a0 + wa * 64 + l16) * 256 + quad * 8;
  bf16x8 areg[8][4];
#pragma unroll
  for (int kk = 0; kk < 8; ++kk)
#pragma unroll
    for (int i = 0; i < 4; ++i)
      areg[kk][i] = *(const bf16x8*)(abase + i * 4096 + kk * 32);

  f32x4 acc[4][4];
#pragma unroll
  for (int i = 0; i < 4; ++i)
#pragma unroll
    for (int j = 0; j < 4; ++j) acc[i][j] = (f32x4){0.f, 0.f, 0.f, 0.f};

  __syncthreads();  // the only barrier

  const int sw = l16 & 7;
#pragma unroll
  for (int kk = 0; kk < 8; ++kk) {
    bf16x8 bf[4];
#pragma unroll
    for (int j = 0; j < 4; ++j) {
      int rr = wt * 64 + j * 16 + l16;
      int c = kk * 4 + quad;
      int pos = (c & 24) | ((c ^ sw) & 7);
      bf[j] = *(const bf16x8*)(&Bsm[rr * 256 + pos * 8]);
    }
#pragma unroll
    for (int i = 0; i < 4; ++i)
#pragma unroll
      for (int j = 0; j < 4; ++j)
        acc[i][j] = __builtin_amdgcn_mfma_f32_16x16x32_bf16(areg[kk][i], bf[j], acc[i][j], 0, 0, 0);
  }
  // store C transposed: M_T[t][a'] -- nontemporal (bypass L2; consumed much
  // later by k_attn2, 111MB stream would thrash the 4MB XCD-L2)
#pragma unroll
  for (int i = 0; i < 4; ++i)
#pragma unroll
    for (int j = 0; j < 4; ++j) {
      int tg = t0 + wt * 64 + j * 16 + l16;
      int ag = a0 + wa * 64 + i * 16 + quad * 4;
      union { ushort4 u; unsigned long long ll; } cv_;
      cv_.u = pack4(acc[i][j]);
      __builtin_nontemporal_store(
          cv_.ll, (unsigned long long*)(Mn + (size_t)tg * MSTR + ag));
    }
}

// ================= attn2 (unchanged) ==============================
#define XP_STR 264
__global__ __launch_bounds__(512, 4) void k_attn2(
    const ushort_t* __restrict__ Xroll, ushort_t* __restrict__ MT,
    const float* __restrict__ relL2) {
  __shared__ ushort_t Xp[64 * XP_STR];
  __shared__ ushort_t StB[2][64 * 72];
  __shared__ float aqsL[8 * 64];
  __shared__ float bpsL[8 * 64];
  __shared__ float relLh[8 * 169];

  const int tid = threadIdx.x;
  const int wave = tid >> 6, lane = tid & 63;
  const int quad = lane >> 4, l16 = lane & 15;
  const int group = wave >> 2, wv = wave & 3;
  const int n = blockIdx.x >> 6, g = blockIdx.x & 63;
  const int gi = g >> 3, gj = g & 7;
  const ushort_t* Xn = Xroll + (size_t)n * TROWS * 256;
  ushort_t* Mn = MT + (size_t)n * TROWS * MSTR;

  {
    const int p = tid & 63, cg = tid >> 6;
    if (p < 49) {
      int t = tmap(p, gi, gj);
#pragma unroll
      for (int i = 0; i < 4; ++i)
        *(u16x8*)(&Xp[p * XP_STR + (cg * 4 + i) * 8]) =
            *(const u16x8*)(Xn + t * 256 + (cg * 4 + i) * 8);
    } else {
#pragma unroll
      for (int i = 0; i < 4; ++i)
        *(u16x8*)(&Xp[p * XP_STR + (cg * 4 + i) * 8]) = (u16x8){0,0,0,0,0,0,0,0};
    }
  }
  for (int i = tid; i < 8 * 169; i += 512) relLh[i] = relL2[i];
  {
    const int h = tid >> 6, q = tid & 63;
    int qq = (q < 49) ? q : 48;
    int t = tmap(qq, gi, gj);
    aqsL[h * 64 + q] = b2f(Mn[(size_t)t * MSTR + 2048 + h]);
    bpsL[h * 64 + q] = b2f(Mn[(size_t)t * MSTR + 2056 + h]);
  }
  __syncthreads();

  bf16x8 xfr[4][2];
#pragma unroll
  for (int dt = 0; dt < 4; ++dt) {
    const int d = (wv * 4 + dt) * 16 + l16;
#pragma unroll
    for (int kk = 0; kk < 2; ++kk)
#pragma unroll
      for (int j = 0; j < 8; ++j)
        xfr[dt][kk][j] = (short)Xp[(kk * 32 + quad * 8 + j) * XP_STR + d];
  }

  const int q = wv * 16 + l16;
  const int qq = (q < 49) ? q : 48;
  const int tq = tmap(qq, gi, gj);
  const ushort_t* Mbase = Mn + (size_t)tq * MSTR + quad * 8;
  const int yq = div7(qq), xq = qq - yq * 7;
  const int fq = regof(gi * 7 + yq) * 3 + regof(gj * 7 + xq);

  for (int hh = 0; hh < 4; ++hh) {
    const int h = hh * 2 + group;
    f32x4 sacc[4];
#pragma unroll
    for (int pt = 0; pt < 4; ++pt) sacc[pt] = (f32x4){0.f, 0.f, 0.f, 0.f};
    const ushort_t* mrow = Mbase + h * 256;
#pragma unroll
    for (int kk = 0; kk < 8; ++kk) {
      bf16x8 bfm = *(const bf16x8*)(mrow + kk * 32);
#pragma unroll
      for (int pt = 0; pt < 4; ++pt) {
        bf16x8 af = *(const bf16x8*)(&Xp[(pt * 16 + l16) * XP_STR + kk * 32 + quad * 8]);
        sacc[pt] = __builtin_amdgcn_mfma_f32_16x16x32_bf16(af, bfm, sacc[pt], 0, 0, 0);
      }
    }
    float v[16];
    const float aqv = aqsL[h * 64 + q];
    const float* rel_h = &relLh[h * 169];
    float m = -1e30f;
#pragma unroll
    for (int pt = 0; pt < 4; ++pt)
#pragma unroll
      for (int r = 0; r < 4; ++r) {
        int p = pt * 16 + quad * 4 + r;
        float val = -1e30f;
        if (p < 49) {
          int yp = div7(p), xp = p - yp * 7;
          int fp = regof(gi * 7 + yp) * 3 + regof(gj * 7 + xp);
          val = (sacc[pt][r] + aqv + bpsL[h * 64 + p]) * 0.0625f +
                rel_h[(yp - yq + 6) + 13 * (xp - xq + 6)];
          if (fp != fq) val -= 100.f;
        }
        v[pt * 4 + r] = val;
        m = fmaxf(m, val);
      }
    m = fmaxf(m, __shfl_xor(m, 16));
    m = fmaxf(m, __shfl_xor(m, 32));
    float s = 0.f;
#pragma unroll
    for (int i = 0; i < 16; ++i) { v[i] = __expf(v[i] - m); s += v[i]; }
    s += __shfl_xor(s, 16);
    s += __shfl_xor(s, 32);
    const float inv = 1.f / s;
    __syncthreads();
    {
      ushort_t* sb = &StB[group][q * 72];
#pragma unroll
      for (int pt = 0; pt < 4; ++pt) {
        ushort4 u;
        u.x = f2b(v[pt * 4 + 0] * inv); u.y = f2b(v[pt * 4 + 1] * inv);
        u.z = f2b(v[pt * 4 + 2] * inv); u.w = f2b(v[pt * 4 + 3] * inv);
        *(ushort4*)(&sb[pt * 16 + quad * 4]) = u;
      }
    }
    __syncthreads();
#pragma unroll
    for (int qt = 0; qt < 4; ++qt) {
      f32x4 tacc[4];
#pragma unroll
      for (int dt = 0; dt < 4; ++dt) tacc[dt] = (f32x4){0.f, 0.f, 0.f, 0.f};
#pragma unroll
      for (int kk = 0; kk < 2; ++kk) {
        bf16x8 bfw = *(const bf16x8*)(&StB[group][(qt * 16 + l16) * 72 + kk * 32 + quad * 8]);
#pragma unroll
        for (int dt = 0; dt < 4; ++dt)
          tacc[dt] = __builtin_amdgcn_mfma_f32_16x16x32_bf16(xfr[dt][kk], bfw, tacc[dt], 0, 0, 0);
      }
      int q2 = qt * 16 + l16;
      if (q2 < 49) {
        int t2 = tmap(q2, gi, gj);
#pragma unroll
        for (int dt = 0; dt < 4; ++dt) {
          int d0 = (wv * 4 + dt) * 16 + quad * 4;
          *(ushort4*)(Mn + (size_t)t2 * MSTR + h * 256 + d0) = pack4(tacc[dt]);
        }
      }
    }
  }
}

// ================= gemm3: out[o][t] = Wov3 . T_T^T + cvec =================
// 128o x 128t tile, BK=128, 16 k-iters, DMA fills with XOR swizzle.
// R7: XCD-bijective swizzle (XCD k owns n=k; Wov3 1MB stays L2-hot, and the
// two oi-blocks sharing a T-tile hit the same L2) + nontemporal out stores.
__global__ __launch_bounds__(256, 2) void k_gemm3(
    const ushort_t* __restrict__ Wov3, const ushort_t* __restrict__ MT,
    const float* __restrict__ cvec, float* __restrict__ out) {
  __shared__ ushort_t Asm[128 * 128];   // 32 KB
  __shared__ ushort_t Bsm[128 * 128];   // 32 KB
  const int bx0 = blockIdx.x;
  const int bx = (bx0 & 7) * 50 + (bx0 >> 3);    // bijective: 400 = 8*50
  const int n = bx / 50, r2 = bx % 50;
  const int oi = r2 / 25, tt = r2 % 25;
  const int o0 = oi * 128, t0 = tt * 128;
  const int tid = threadIdx.x, wave = tid >> 6, lane = tid & 63;
  const int quad = lane >> 4, l16 = lane & 15;
  const int wa = wave >> 1, wt = wave & 1;
  const ushort_t* Tn = MT + (size_t)n * TROWS * MSTR;
  float* on = out + (size_t)n * 256 * 3136;
  const int sw = l16 & 7;

  f32x4 acc[4][4];
#pragma unroll
  for (int i = 0; i < 4; ++i)
#pragma unroll
    for (int j = 0; j < 4; ++j) acc[i][j] = (f32x4){0.f, 0.f, 0.f, 0.f};

  for (int kit = 0; kit < 16; ++kit) {
    const int kb = kit * 128;
    // fill A[128][128] and B[128][128], 16B chunks, swizzle c^=(r&7)
#pragma unroll
    for (int i = 0; i < 8; ++i) {
      int S = i * 256 + tid;
      int rr = S >> 4, sc = S & 15;
      int c = (sc & 8) | ((sc ^ rr) & 7);
      gload_lds16(Wov3 + (o0 + rr) * 2048 + kb + c * 8,
                  &Asm[(i * 256 + wave * 64) * 8]);
    }
#pragma unroll
    for (int i = 0; i < 8; ++i) {
      int S = i * 256 + tid;
      int rr = S >> 4, sc = S & 15;
      int c = (sc & 8) | ((sc ^ rr) & 7);
      gload_lds16(Tn + (size_t)(t0 + rr) * MSTR + kb + c * 8,
                  &Bsm[(i * 256 + wave * 64) * 8]);
    }
    __syncthreads();
#pragma unroll
    for (int kk = 0; kk < 4; ++kk) {
      bf16x8 af[4], bf[4];
      const int c = kk * 4 + quad;
      const int pos = (c & 8) | ((c ^ sw) & 7);
#pragma unroll
      for (int i = 0; i < 4; ++i)
        af[i] = *(const bf16x8*)(&Asm[(wa * 64 + i * 16 + l16) * 128 + pos * 8]);
#pragma unroll
      for (int j = 0; j < 4; ++j)
        bf[j] = *(const bf16x8*)(&Bsm[(wt * 64 + j * 16 + l16) * 128 + pos * 8]);
#pragma unroll
      for (int i = 0; i < 4; ++i)
#pragma unroll
        for (int j = 0; j < 4; ++j)
          acc[i][j] = __builtin_amdgcn_mfma_f32_16x16x32_bf16(af[i], bf[j], acc[i][j], 0, 0, 0);
    }
    __syncthreads();
  }
  // epilogue: + cvec, guard pad tokens; nontemporal stores (25.7MB stream,
  // never re-read on device)
#pragma unroll
  for (int i = 0; i < 4; ++i) {
    const int ob = o0 + wa * 64 + i * 16 + quad * 4;
    const float4 cv = *(const float4*)(cvec + ob);
#pragma unroll
    for (int j = 0; j < 4; ++j) {
      const int tg = t0 + wt * 64 + j * 16 + l16;
      if (tg < 3136) {
        __builtin_nontemporal_store(acc[i][j][0] + cv.x, &on[(size_t)(ob + 0) * 3136 + tg]);
        __builtin_nontemporal_store(acc[i][j][1] + cv.y, &on[(size_t)(ob + 1) * 3136 + tg]);
        __builtin_nontemporal_store(acc[i][j][2] + cv.z, &on[(size_t)(ob + 2) * 3136 + tg]);
        __builtin_nontemporal_store(acc[i][j][3] + cv.w, &on[(size_t)(ob + 3) * 3136 + tg]);
      }
    }
  }
}

extern "C" void kernel_launch(void* const* d_in, const int* in_sizes, int n_in,
                              void* d_out, int out_size, void* d_ws, size_t ws_size,
                              hipStream_t stream) {
  (void)in_sizes; (void)n_in; (void)out_size; (void)ws_size;
  const float* X  = (const float*)d_in[0];
  const float* Wk = (const float*)d_in[1];
  const float* bk = (const float*)d_in[2];
  const float* Wq = (const float*)d_in[3];
  const float* bq = (const float*)d_in[4];
  const float* Wv = (const float*)d_in[5];
  const float* bv = (const float*)d_in[6];
  const float* Wo = (const float*)d_in[7];
  const float* bo = (const float*)d_in[8];
  const float* rc = (const float*)d_in[9];

  ushort_t* MT    = (ushort_t*)d_ws;                       // 8*3200*2176 u16
  ushort_t* Xroll = MT + (size_t)8 * TROWS * MSTR;         // 8*3200*256 u16
  ushort_t* Aext  = Xroll + (size_t)8 * TROWS * 256;       // 2176*256 u16
  ushort_t* Wov3  = Aext + 2176 * 256;                     // 256*2048 u16
  float* fbase = (float*)(Wov3 + 256 * 2048);
  float* cvec  = fbase;         // 256 f32
  float* relL2 = fbase + 256;   // 8*169 f32
  float* out = (float*)d_out;

  k_prep <<<dim3(1290), dim3(256), 0, stream>>>(Wk, Wq, Wo, Wv, bk, bq, bv, bo, rc,
                                                Aext, Wov3, cvec, relL2);
  k_conv <<<dim3(8 * 57), dim3(256), 0, stream>>>(X, Xroll);
  k_gemm1<<<dim3(8 * 425), dim3(256), 0, stream>>>(Xroll, Aext, MT);
  k_attn2<<<dim3(8 * 64), dim3(512), 0, stream>>>(Xroll, MT, relL2);
  k_gemm3<<<dim3(8 * 50), dim3(256), 0, stream>>>(Wov3, MT, cvec, out);
}

// Round 2
// 278.240 us; speedup vs baseline: 1.2385x; 1.2385x over previous
//
#include <hip/hip_runtime.h>
#include <hip/hip_bf16.h>

// Swin window MHSA, MI355X, round 8.
//   k_prep : Aext[2176x256]=G'(+w1/w2 rows), Wov3[256x2048], cvec, relL2(+c0)
//   k_conv : X fp32 -> rolled bf16 Xroll[n][3200][256]  (coalesced stores)
//   k_gemm1: M_T[t][a'] = Xroll . Aext^T
//            R8: PERSISTENT pipelined blocks. Each block owns one (n,aa)
//            A-slice (128a x 256k, in regs: 64 VGPR/wave) and streams 6-7
//            t-tiles of 64 rows with double-buffered LDS (2x32KB), raw
//            s_barrier + COUNTED s_waitcnt vmcnt(16/8) -- fills stay in
//            flight across barriers (T3/T4). XCD swizzle kept; NT stores
//            reverted (they inflated writes 109->195MB via partial lines).
//   k_attn2: per (n,window): S=Xp.M, softmax, T=X.wmap; T overwrites M in-place
//   k_gemm3: out[o][t] = Wov3 . T_T^T + cvec  -- 128x128, BK=128, DMA fills
//            R8: swizzle kept, NT stores reverted.

#define NBATCH 8
#define MSTR   2176           // M_T / T_T row stride (a'-dim, 17 tiles of 128)
#define TROWS  3200           // padded token rows (50 tiles of 64)

typedef unsigned short ushort_t;
typedef __attribute__((ext_vector_type(8))) short bf16x8;   // 8 bf16 = 4 VGPR
typedef __attribute__((ext_vector_type(8))) unsigned short u16x8;
typedef __attribute__((ext_vector_type(4))) float f32x4;    // MFMA acc

__device__ __forceinline__ float b2f(ushort_t u) {
  union { unsigned int i; float f; } v; v.i = ((unsigned int)u) << 16; return v.f;
}
__device__ __forceinline__ ushort_t f2b(float f) {
  union { float f; unsigned int u; } v; v.f = f;
  unsigned int u = v.u;
  return (ushort_t)((u + 0x7FFFu + ((u >> 16) & 1u)) >> 16);
}
__device__ __forceinline__ int regof(int y) { return (y < 49) ? 0 : ((y < 53) ? 1 : 2); }
__device__ __forceinline__ int div7(int t) { return (t * 37) >> 8; }  // t/7, t<64
__device__ __forceinline__ int tmap(int p, int gi, int gj) {
  int wi = div7(p); return (gi * 7 + wi) * 56 + gj * 7 + (p - wi * 7);
}
__device__ __forceinline__ ushort4 pack4(f32x4 a) {
  ushort4 u; u.x = f2b(a[0]); u.y = f2b(a[1]); u.z = f2b(a[2]); u.w = f2b(a[3]);
  return u;
}
// async global->LDS, 16B per lane; lds dest must be wave-uniform base
__device__ __forceinline__ void gload_lds16(const ushort_t* g, ushort_t* l) {
  __builtin_amdgcn_global_load_lds(
      (const __attribute__((address_space(1))) void*)g,
      (__attribute__((address_space(3))) void*)l, 16, 0, 0);
}
__device__ __forceinline__ void sb0() { __builtin_amdgcn_sched_barrier(0); }

// ================= prep (unchanged) =================
__global__ void k_prep(const float* __restrict__ Wk, const float* __restrict__ Wq,
                       const float* __restrict__ Wo, const float* __restrict__ Wv,
                       const float* __restrict__ bk, const float* __restrict__ bq,
                       const float* __restrict__ bv, const float* __restrict__ bo,
                       const float* __restrict__ relc,
                       ushort_t* __restrict__ Aext, ushort_t* __restrict__ Wov3,
                       float* __restrict__ cvec, float* __restrict__ relL2) {
  __shared__ float red[8];
  int blk = blockIdx.x, t = threadIdx.x;
  if (blk < 512) {
    int h = blk >> 6, b0 = (blk & 63) << 2, a = t;
    const float* wkh = Wk + h * 65536;
    const float* wqh = Wq + h * 65536;
    float a0 = 0.f, a1 = 0.f, a2 = 0.f, a3 = 0.f;
    for (int dd = 0; dd < 256; ++dd) {
      float wk = wkh[dd * 256 + a];
      float4 w4 = *(const float4*)(wqh + dd * 256 + b0);
      a0 += wk * w4.x; a1 += wk * w4.y; a2 += wk * w4.z; a3 += wk * w4.w;
    }
    ushort4 u; u.x = f2b(a0); u.y = f2b(a1); u.z = f2b(a2); u.w = f2b(a3);
    *(ushort4*)(Aext + (h * 256 + a) * 256 + b0) = u;
  } else if (blk < 1024) {
    int bb = blk - 512;
    int h = bb >> 6, o0 = (bb & 63) << 2, d = t;
    float a0 = 0.f, a1 = 0.f, a2 = 0.f, a3 = 0.f;
    for (int dd = 0; dd < 256; ++dd) {
      float wv = Wv[(h * 256 + dd) * 256 + d];
      a0 += Wo[(o0 + 0) * 2048 + h * 256 + dd] * wv;
      a1 += Wo[(o0 + 1) * 2048 + h * 256 + dd] * wv;
      a2 += Wo[(o0 + 2) * 2048 + h * 256 + dd] * wv;
      a3 += Wo[(o0 + 3) * 2048 + h * 256 + dd] * wv;
    }
    Wov3[(o0 + 0) * 2048 + h * 256 + d] = f2b(a0);
    Wov3[(o0 + 1) * 2048 + h * 256 + d] = f2b(a1);
    Wov3[(o0 + 2) * 2048 + h * 256 + d] = f2b(a2);
    Wov3[(o0 + 3) * 2048 + h * 256 + d] = f2b(a3);
  } else if (blk < 1032) {
    int h = blk - 1024;
    float s1 = 0.f, s2 = 0.f;
    for (int dd = 0; dd < 256; ++dd) {
      s1 += bk[h * 256 + dd] * Wq[(h * 256 + dd) * 256 + t];
      s2 += bq[h * 256 + dd] * Wk[(h * 256 + dd) * 256 + t];
    }
    Aext[(2048 + h) * 256 + t] = f2b(s1);
    Aext[(2056 + h) * 256 + t] = f2b(s2);
  } else if (blk == 1032) {
    for (int i = t; i < 112 * 256 / 8; i += 256)
      *(u16x8*)(Aext + 2064 * 256 + i * 8) = (u16x8){0,0,0,0,0,0,0,0};
  } else if (blk < 1289) {
    int o = blk - 1033;
    const float* wob = Wo + o * 2048;
    float acc = 0.f;
#pragma unroll
    for (int j = 0; j < 8; ++j) acc += wob[j * 256 + t] * bv[j * 256 + t];
#pragma unroll
    for (int s = 1; s < 64; s <<= 1) acc += __shfl_xor(acc, s);
    if ((t & 63) == 0) red[t >> 6] = acc;
    __syncthreads();
    if (t == 0) cvec[o] = bo[o] + red[0] + red[1] + red[2] + red[3];
  } else {
    if (t < 8) {
      float c = 0.f;
      for (int dd = 0; dd < 256; ++dd) c += bk[t * 256 + dd] * bq[t * 256 + dd];
      red[t] = c * 0.0625f;
    }
    __syncthreads();
    for (int i = t; i < 8 * 169; i += 256) {
      int h = i / 169, idx = i - h * 169;
      relL2[i] = relc[idx * 8 + h] + red[h];
    }
  }
}

// ================= conv: rolled gather, coalesced bf16 stores =============
__global__ void k_conv(const float* __restrict__ X, ushort_t* __restrict__ Xroll) {
  const int n = blockIdx.x / 57, y = blockIdx.x % 57;
  ushort_t* xr = Xroll + (size_t)n * TROWS * 256;
  const int d = threadIdx.x;
  if (y == 56) {  // zero pad rows 3136..3199
    for (int i = d; i < 64 * 256 / 8; i += 256)
      *(u16x8*)(xr + 3136 * 256 + i * 8) = (u16x8){0,0,0,0,0,0,0,0};
    return;
  }
  const int c = d >> 4, p1 = (d >> 2) & 3, p2 = d & 3;
  const int sp = c * 16 + (((p1 + 1) & 3) << 2) + ((p2 + 1) & 3);
  const int ty = (p1 == 3) ? y : ((y == 0) ? 55 : y - 1);
  const float* rowp = X + (size_t)n * 256 * 3136 + sp * 3136 + ty * 56;
  ushort_t* orow = xr + y * 56 * 256 + d;
  for (int x = 0; x < 56; ++x) {
    int tx = (p2 == 3) ? x : ((x == 0) ? 55 : x - 1);
    orow[x * 256] = f2b(rowp[tx]);   // 256 lanes -> 512B contiguous store
  }
}

// ================= gemm1: M_T[t][a'] = Xroll . Aext^T =====================
// R8 persistent pipelined version. Block = (n = XCD, aa, chunk c).
//   - A-slice aa (128a x 256k): each wave owns 32 a-rows in regs
//     (areg[8][2] = 64 VGPR), loaded once, live across the t-loop (rolled
//     loop => LICM keeps them resident).
//   - t-loop: 6-7 tiles of 64 t-rows. B-tile 64x256 (32KB) double-buffered.
//     fill(m+1)/fill(m+2) stay in flight across raw s_barriers; waits are
//     COUNTED: vmcnt(16) = stores(m-1)[8] + fill(m+1)[8] may remain.
//   - sched_barrier(0) fences pin the VMEM group order so counts stay valid.
__global__ __launch_bounds__(256, 2) void k_gemm1(
    const ushort_t* __restrict__ Xroll, const ushort_t* __restrict__ Aext,
    ushort_t* __restrict__ MT) {
  __shared__ ushort_t Bsm[2][64 * 256];   // 2 x 32 KB
  const int bx0 = blockIdx.x;
  const int n = bx0 & 7;                  // XCD-bijective: XCD k owns batch k
  const int inner = bx0 >> 3;             // 0..135
  const int aa = inner % 17;
  const int c  = inner / 17;              // chunk 0..7
  const int a0 = aa * 128;
  const int tstart = c * 6 + ((c < 2) ? c : 2);   // in 64-row tiles
  const int T = 6 + ((c < 2) ? 1 : 0);            // 2x7 + 6x6 = 50 tiles
  const int tid = threadIdx.x, wave = tid >> 6, lane = tid & 63;
  const int quad = lane >> 4, l16 = lane & 15;
  const ushort_t* Xn = Xroll + (size_t)n * TROWS * 256;
  ushort_t* Mn = MT + (size_t)n * TROWS * MSTR;

  // ---- A-slice into regs: wave owns rows [a0+wave*32, +32), full K ----
  const ushort_t* abase = Aext + (size_t)(a0 + wave * 32 + l16) * 256 + quad * 8;
  bf16x8 areg[8][2];
#pragma unroll
  for (int kk = 0; kk < 8; ++kk)
#pragma unroll
    for (int i = 0; i < 2; ++i)
      areg[kk][i] = *(const bf16x8*)(abase + i * 4096 + kk * 32);   // 16 loads
  sb0();

  // ---- DMA fill of one 64x256 tile (swizzled), 8 insts/wave ----
  auto fill = [&](int mt, int b) {
    const ushort_t* src = Xn + (size_t)(tstart + mt) * 64 * 256;
#pragma unroll
    for (int i = 0; i < 8; ++i) {
      int S = i * 256 + tid;
      int rr = S >> 5, sc = S & 31;
      int cc = (sc & 24) | ((sc ^ rr) & 7);
      gload_lds16(src + rr * 256 + cc * 8, &Bsm[b][(i * 256 + wave * 64) * 8]);
    }
  };

  fill(0, 0); sb0();
  fill(1, 1); sb0();
  // outstanding: A(16), f0(8), f1(8). Wait to 8 => A + f0 complete.
  asm volatile("s_waitcnt vmcnt(8)" ::: "memory"); sb0();
  __builtin_amdgcn_s_barrier(); sb0();

  const int sw = l16 & 7;
  for (int m = 0; m < T; ++m) {
    if (m > 0) {
      // need fill(m) done. Issued after it: stores(m-1)[8] (+ fill(m+1)[8]).
      if (m + 1 < T) { asm volatile("s_waitcnt vmcnt(16)" ::: "memory"); }
      else           { asm volatile("s_waitcnt vmcnt(8)"  ::: "memory"); }
      sb0();
      __builtin_amdgcn_s_barrier(); sb0();
    }
    const int b = m & 1;
    f32x4 acc[2][4];
#pragma unroll
    for (int i = 0; i < 2; ++i)
#pragma unroll
      for (int j = 0; j < 4; ++j) acc[i][j] = (f32x4){0.f, 0.f, 0.f, 0.f};
#pragma unroll
    for (int kk = 0; kk < 8; ++kk) {
      bf16x8 bfj[4];
#pragma unroll
      for (int j = 0; j < 4; ++j) {
        int rr = j * 16 + l16;
        int cc = kk * 4 + quad;
        int pos = (cc & 24) | ((cc ^ sw) & 7);
        bfj[j] = *(const bf16x8*)(&Bsm[b][rr * 256 + pos * 8]);
      }
#pragma unroll
      for (int i = 0; i < 2; ++i)
#pragma unroll
        for (int j = 0; j < 4; ++j)
          acc[i][j] = __builtin_amdgcn_mfma_f32_16x16x32_bf16(areg[kk][i], bfj[j], acc[i][j], 0, 0, 0);
    }
    // stores: 8 per wave (counted in the vmcnt schedule)
    const int tb = (tstart + m) * 64;
#pragma unroll
    for (int i = 0; i < 2; ++i)
#pragma unroll
      for (int j = 0; j < 4; ++j) {
        int tg = tb + j * 16 + l16;
        int ag = a0 + wave * 32 + i * 16 + quad * 4;
        *(ushort4*)(Mn + (size_t)tg * MSTR + ag) = pack4(acc[i][j]);
      }
    sb0();
    __builtin_amdgcn_s_barrier(); sb0();   // all waves done reading buf b
    if (m + 2 < T) { fill(m + 2, b); sb0(); }
  }
}

// ================= attn2 (unchanged) ==============================
#define XP_STR 264
__global__ __launch_bounds__(512, 4) void k_attn2(
    const ushort_t* __restrict__ Xroll, ushort_t* __restrict__ MT,
    const float* __restrict__ relL2) {
  __shared__ ushort_t Xp[64 * XP_STR];
  __shared__ ushort_t StB[2][64 * 72];
  __shared__ float aqsL[8 * 64];
  __shared__ float bpsL[8 * 64];
  __shared__ float relLh[8 * 169];

  const int tid = threadIdx.x;
  const int wave = tid >> 6, lane = tid & 63;
  const int quad = lane >> 4, l16 = lane & 15;
  const int group = wave >> 2, wv = wave & 3;
  const int n = blockIdx.x >> 6, g = blockIdx.x & 63;
  const int gi = g >> 3, gj = g & 7;
  const ushort_t* Xn = Xroll + (size_t)n * TROWS * 256;
  ushort_t* Mn = MT + (size_t)n * TROWS * MSTR;

  {
    const int p = tid & 63, cg = tid >> 6;
    if (p < 49) {
      int t = tmap(p, gi, gj);
#pragma unroll
      for (int i = 0; i < 4; ++i)
        *(u16x8*)(&Xp[p * XP_STR + (cg * 4 + i) * 8]) =
            *(const u16x8*)(Xn + t * 256 + (cg * 4 + i) * 8);
    } else {
#pragma unroll
      for (int i = 0; i < 4; ++i)
        *(u16x8*)(&Xp[p * XP_STR + (cg * 4 + i) * 8]) = (u16x8){0,0,0,0,0,0,0,0};
    }
  }
  for (int i = tid; i < 8 * 169; i += 512) relLh[i] = relL2[i];
  {
    const int h = tid >> 6, q = tid & 63;
    int qq = (q < 49) ? q : 48;
    int t = tmap(qq, gi, gj);
    aqsL[h * 64 + q] = b2f(Mn[(size_t)t * MSTR + 2048 + h]);
    bpsL[h * 64 + q] = b2f(Mn[(size_t)t * MSTR + 2056 + h]);
  }
  __syncthreads();

  bf16x8 xfr[4][2];
#pragma unroll
  for (int dt = 0; dt < 4; ++dt) {
    const int d = (wv * 4 + dt) * 16 + l16;
#pragma unroll
    for (int kk = 0; kk < 2; ++kk)
#pragma unroll
      for (int j = 0; j < 8; ++j)
        xfr[dt][kk][j] = (short)Xp[(kk * 32 + quad * 8 + j) * XP_STR + d];
  }

  const int q = wv * 16 + l16;
  const int qq = (q < 49) ? q : 48;
  const int tq = tmap(qq, gi, gj);
  const ushort_t* Mbase = Mn + (size_t)tq * MSTR + quad * 8;
  const int yq = div7(qq), xq = qq - yq * 7;
  const int fq = regof(gi * 7 + yq) * 3 + regof(gj * 7 + xq);

  for (int hh = 0; hh < 4; ++hh) {
    const int h = hh * 2 + group;
    f32x4 sacc[4];
#pragma unroll
    for (int pt = 0; pt < 4; ++pt) sacc[pt] = (f32x4){0.f, 0.f, 0.f, 0.f};
    const ushort_t* mrow = Mbase + h * 256;
#pragma unroll
    for (int kk = 0; kk < 8; ++kk) {
      bf16x8 bfm = *(const bf16x8*)(mrow + kk * 32);
#pragma unroll
      for (int pt = 0; pt < 4; ++pt) {
        bf16x8 af = *(const bf16x8*)(&Xp[(pt * 16 + l16) * XP_STR + kk * 32 + quad * 8]);
        sacc[pt] = __builtin_amdgcn_mfma_f32_16x16x32_bf16(af, bfm, sacc[pt], 0, 0, 0);
      }
    }
    float v[16];
    const float aqv = aqsL[h * 64 + q];
    const float* rel_h = &relLh[h * 169];
    float m = -1e30f;
#pragma unroll
    for (int pt = 0; pt < 4; ++pt)
#pragma unroll
      for (int r = 0; r < 4; ++r) {
        int p = pt * 16 + quad * 4 + r;
        float val = -1e30f;
        if (p < 49) {
          int yp = div7(p), xp = p - yp * 7;
          int fp = regof(gi * 7 + yp) * 3 + regof(gj * 7 + xp);
          val = (sacc[pt][r] + aqv + bpsL[h * 64 + p]) * 0.0625f +
                rel_h[(yp - yq + 6) + 13 * (xp - xq + 6)];
          if (fp != fq) val -= 100.f;
        }
        v[pt * 4 + r] = val;
        m = fmaxf(m, val);
      }
    m = fmaxf(m, __shfl_xor(m, 16));
    m = fmaxf(m, __shfl_xor(m, 32));
    float s = 0.f;
#pragma unroll
    for (int i = 0; i < 16; ++i) { v[i] = __expf(v[i] - m); s += v[i]; }
    s += __shfl_xor(s, 16);
    s += __shfl_xor(s, 32);
    const float inv = 1.f / s;
    __syncthreads();
    {
      ushort_t* sb = &StB[group][q * 72];
#pragma unroll
      for (int pt = 0; pt < 4; ++pt) {
        ushort4 u;
        u.x = f2b(v[pt * 4 + 0] * inv); u.y = f2b(v[pt * 4 + 1] * inv);
        u.z = f2b(v[pt * 4 + 2] * inv); u.w = f2b(v[pt * 4 + 3] * inv);
        *(ushort4*)(&sb[pt * 16 + quad * 4]) = u;
      }
    }
    __syncthreads();
#pragma unroll
    for (int qt = 0; qt < 4; ++qt) {
      f32x4 tacc[4];
#pragma unroll
      for (int dt = 0; dt < 4; ++dt) tacc[dt] = (f32x4){0.f, 0.f, 0.f, 0.f};
#pragma unroll
      for (int kk = 0; kk < 2; ++kk) {
        bf16x8 bfw = *(const bf16x8*)(&StB[group][(qt * 16 + l16) * 72 + kk * 32 + quad * 8]);
#pragma unroll
        for (int dt = 0; dt < 4; ++dt)
          tacc[dt] = __builtin_amdgcn_mfma_f32_16x16x32_bf16(xfr[dt][kk], bfw, tacc[dt], 0, 0, 0);
      }
      int q2 = qt * 16 + l16;
      if (q2 < 49) {
        int t2 = tmap(q2, gi, gj);
#pragma unroll
        for (int dt = 0; dt < 4; ++dt) {
          int d0 = (wv * 4 + dt) * 16 + quad * 4;
          *(ushort4*)(Mn + (size_t)t2 * MSTR + h * 256 + d0) = pack4(tacc[dt]);
        }
      }
    }
  }
}

// ================= gemm3: out[o][t] = Wov3 . T_T^T + cvec =================
// 128o x 128t tile, BK=128, 16 k-iters, DMA fills with XOR swizzle.
// R8: swizzle kept (XCD k owns n=k; Wov3 1MB stays L2-hot), NT stores
// reverted (partial-line write inflation).
__global__ __launch_bounds__(256, 2) void k_gemm3(
    const ushort_t* __restrict__ Wov3, const ushort_t* __restrict__ MT,
    const float* __restrict__ cvec, float* __restrict__ out) {
  __shared__ ushort_t Asm[128 * 128];   // 32 KB
  __shared__ ushort_t Bsm[128 * 128];   // 32 KB
  const int bx0 = blockIdx.x;
  const int bx = (bx0 & 7) * 50 + (bx0 >> 3);    // bijective: 400 = 8*50
  const int n = bx / 50, r2 = bx % 50;
  const int oi = r2 / 25, tt = r2 % 25;
  const int o0 = oi * 128, t0 = tt * 128;
  const int tid = threadIdx.x, wave = tid >> 6, lane = tid & 63;
  const int quad = lane >> 4, l16 = lane & 15;
  const int wa = wave >> 1, wt = wave & 1;
  const ushort_t* Tn = MT + (size_t)n * TROWS * MSTR;
  float* on = out + (size_t)n * 256 * 3136;
  const int sw = l16 & 7;

  f32x4 acc[4][4];
#pragma unroll
  for (int i = 0; i < 4; ++i)
#pragma unroll
    for (int j = 0; j < 4; ++j) acc[i][j] = (f32x4){0.f, 0.f, 0.f, 0.f};

  for (int kit = 0; kit < 16; ++kit) {
    const int kb = kit * 128;
    // fill A[128][128] and B[128][128], 16B chunks, swizzle c^=(r&7)
#pragma unroll
    for (int i = 0; i < 8; ++i) {
      int S = i * 256 + tid;
      int rr = S >> 4, sc = S & 15;
      int c = (sc & 8) | ((sc ^ rr) & 7);
      gload_lds16(Wov3 + (o0 + rr) * 2048 + kb + c * 8,
                  &Asm[(i * 256 + wave * 64) * 8]);
    }
#pragma unroll
    for (int i = 0; i < 8; ++i) {
      int S = i * 256 + tid;
      int rr = S >> 4, sc = S & 15;
      int c = (sc & 8) | ((sc ^ rr) & 7);
      gload_lds16(Tn + (size_t)(t0 + rr) * MSTR + kb + c * 8,
                  &Bsm[(i * 256 + wave * 64) * 8]);
    }
    __syncthreads();
#pragma unroll
    for (int kk = 0; kk < 4; ++kk) {
      bf16x8 af[4], bf[4];
      const int c = kk * 4 + quad;
      const int pos = (c & 8) | ((c ^ sw) & 7);
#pragma unroll
      for (int i = 0; i < 4; ++i)
        af[i] = *(const bf16x8*)(&Asm[(wa * 64 + i * 16 + l16) * 128 + pos * 8]);
#pragma unroll
      for (int j = 0; j < 4; ++j)
        bf[j] = *(const bf16x8*)(&Bsm[(wt * 64 + j * 16 + l16) * 128 + pos * 8]);
#pragma unroll
      for (int i = 0; i < 4; ++i)
#pragma unroll
        for (int j = 0; j < 4; ++j)
          acc[i][j] = __builtin_amdgcn_mfma_f32_16x16x32_bf16(af[i], bf[j], acc[i][j], 0, 0, 0);
    }
    __syncthreads();
  }
  // epilogue: + cvec, guard pad tokens (regular stores -> L2 write-combining)
#pragma unroll
  for (int i = 0; i < 4; ++i) {
    const int ob = o0 + wa * 64 + i * 16 + quad * 4;
    const float4 cv = *(const float4*)(cvec + ob);
#pragma unroll
    for (int j = 0; j < 4; ++j) {
      const int tg = t0 + wt * 64 + j * 16 + l16;
      if (tg < 3136) {
        on[(size_t)(ob + 0) * 3136 + tg] = acc[i][j][0] + cv.x;
        on[(size_t)(ob + 1) * 3136 + tg] = acc[i][j][1] + cv.y;
        on[(size_t)(ob + 2) * 3136 + tg] = acc[i][j][2] + cv.z;
        on[(size_t)(ob + 3) * 3136 + tg] = acc[i][j][3] + cv.w;
      }
    }
  }
}

extern "C" void kernel_launch(void* const* d_in, const int* in_sizes, int n_in,
                              void* d_out, int out_size, void* d_ws, size_t ws_size,
                              hipStream_t stream) {
  (void)in_sizes; (void)n_in; (void)out_size; (void)ws_size;
  const float* X  = (const float*)d_in[0];
  const float* Wk = (const float*)d_in[1];
  const float* bk = (const float*)d_in[2];
  const float* Wq = (const float*)d_in[3];
  const float* bq = (const float*)d_in[4];
  const float* Wv = (const float*)d_in[5];
  const float* bv = (const float*)d_in[6];
  const float* Wo = (const float*)d_in[7];
  const float* bo = (const float*)d_in[8];
  const float* rc = (const float*)d_in[9];

  ushort_t* MT    = (ushort_t*)d_ws;                       // 8*3200*2176 u16
  ushort_t* Xroll = MT + (size_t)8 * TROWS * MSTR;         // 8*3200*256 u16
  ushort_t* Aext  = Xroll + (size_t)8 * TROWS * 256;       // 2176*256 u16
  ushort_t* Wov3  = Aext + 2176 * 256;                     // 256*2048 u16
  float* fbase = (float*)(Wov3 + 256 * 2048);
  float* cvec  = fbase;         // 256 f32
  float* relL2 = fbase + 256;   // 8*169 f32
  float* out = (float*)d_out;

  k_prep <<<dim3(1290), dim3(256), 0, stream>>>(Wk, Wq, Wo, Wv, bk, bq, bv, bo, rc,
                                                Aext, Wov3, cvec, relL2);
  k_conv <<<dim3(8 * 57), dim3(256), 0, stream>>>(X, Xroll);
  k_gemm1<<<dim3(8 * 136), dim3(256), 0, stream>>>(Xroll, Aext, MT);
  k_attn2<<<dim3(8 * 64), dim3(512), 0, stream>>>(Xroll, MT, relL2);
  k_gemm3<<<dim3(8 * 50), dim3(256), 0, stream>>>(Wov3, MT, cvec, out);
}

// Round 3
// 274.219 us; speedup vs baseline: 1.2567x; 1.0147x over previous
//
#include <hip/hip_runtime.h>
#include <hip/hip_bf16.h>

// Swin window MHSA, MI355X, round 9.
//   k_prep : Aext[2176x256]=G'(+w1/w2 rows), Wov3[256x2048], cvec, relL2(+c0)
//   k_conv : X fp32 -> rolled bf16 Xroll[n][3200][256]  (coalesced stores)
//   k_gemm1: M_T[t][a'] = Xroll . Aext^T
//            R9: persistent pipelined blocks (R8 structure) with
//            (a) 4a x 2t wave geometry: areg[8][4]=128 VGPR per wave,
//                2 B-reads -> 16 MFMAs per kk (R8 was 4 reads -> 8 MFMAs;
//                LDS-read-bound at 12cyc/b128). Halves LDS read traffic.
//            (b) round-balanced grid: 119 blocks/XCD (17aa x 7 chunks)
//                = rounds of 64/55 vs R8's 64/64/8 tail.
//   k_attn2: per (n,window): S=Xp.M, softmax, T=X.wmap; T overwrites M in-place
//   k_gemm3: out[o][t] = Wov3 . T_T^T + cvec  -- 128x128, BK=128, DMA fills

#define NBATCH 8
#define MSTR   2176           // M_T / T_T row stride (a'-dim, 17 tiles of 128)
#define TROWS  3200           // padded token rows (50 tiles of 64)

typedef unsigned short ushort_t;
typedef __attribute__((ext_vector_type(8))) short bf16x8;   // 8 bf16 = 4 VGPR
typedef __attribute__((ext_vector_type(8))) unsigned short u16x8;
typedef __attribute__((ext_vector_type(4))) float f32x4;    // MFMA acc

__device__ __forceinline__ float b2f(ushort_t u) {
  union { unsigned int i; float f; } v; v.i = ((unsigned int)u) << 16; return v.f;
}
__device__ __forceinline__ ushort_t f2b(float f) {
  union { float f; unsigned int u; } v; v.f = f;
  unsigned int u = v.u;
  return (ushort_t)((u + 0x7FFFu + ((u >> 16) & 1u)) >> 16);
}
__device__ __forceinline__ int regof(int y) { return (y < 49) ? 0 : ((y < 53) ? 1 : 2); }
__device__ __forceinline__ int div7(int t) { return (t * 37) >> 8; }  // t/7, t<64
__device__ __forceinline__ int tmap(int p, int gi, int gj) {
  int wi = div7(p); return (gi * 7 + wi) * 56 + gj * 7 + (p - wi * 7);
}
__device__ __forceinline__ ushort4 pack4(f32x4 a) {
  ushort4 u; u.x = f2b(a[0]); u.y = f2b(a[1]); u.z = f2b(a[2]); u.w = f2b(a[3]);
  return u;
}
// async global->LDS, 16B per lane; lds dest must be wave-uniform base
__device__ __forceinline__ void gload_lds16(const ushort_t* g, ushort_t* l) {
  __builtin_amdgcn_global_load_lds(
      (const __attribute__((address_space(1))) void*)g,
      (__attribute__((address_space(3))) void*)l, 16, 0, 0);
}
__device__ __forceinline__ void sb0() { __builtin_amdgcn_sched_barrier(0); }

// ================= prep (unchanged) =================
__global__ void k_prep(const float* __restrict__ Wk, const float* __restrict__ Wq,
                       const float* __restrict__ Wo, const float* __restrict__ Wv,
                       const float* __restrict__ bk, const float* __restrict__ bq,
                       const float* __restrict__ bv, const float* __restrict__ bo,
                       const float* __restrict__ relc,
                       ushort_t* __restrict__ Aext, ushort_t* __restrict__ Wov3,
                       float* __restrict__ cvec, float* __restrict__ relL2) {
  __shared__ float red[8];
  int blk = blockIdx.x, t = threadIdx.x;
  if (blk < 512) {
    int h = blk >> 6, b0 = (blk & 63) << 2, a = t;
    const float* wkh = Wk + h * 65536;
    const float* wqh = Wq + h * 65536;
    float a0 = 0.f, a1 = 0.f, a2 = 0.f, a3 = 0.f;
    for (int dd = 0; dd < 256; ++dd) {
      float wk = wkh[dd * 256 + a];
      float4 w4 = *(const float4*)(wqh + dd * 256 + b0);
      a0 += wk * w4.x; a1 += wk * w4.y; a2 += wk * w4.z; a3 += wk * w4.w;
    }
    ushort4 u; u.x = f2b(a0); u.y = f2b(a1); u.z = f2b(a2); u.w = f2b(a3);
    *(ushort4*)(Aext + (h * 256 + a) * 256 + b0) = u;
  } else if (blk < 1024) {
    int bb = blk - 512;
    int h = bb >> 6, o0 = (bb & 63) << 2, d = t;
    float a0 = 0.f, a1 = 0.f, a2 = 0.f, a3 = 0.f;
    for (int dd = 0; dd < 256; ++dd) {
      float wv = Wv[(h * 256 + dd) * 256 + d];
      a0 += Wo[(o0 + 0) * 2048 + h * 256 + dd] * wv;
      a1 += Wo[(o0 + 1) * 2048 + h * 256 + dd] * wv;
      a2 += Wo[(o0 + 2) * 2048 + h * 256 + dd] * wv;
      a3 += Wo[(o0 + 3) * 2048 + h * 256 + dd] * wv;
    }
    Wov3[(o0 + 0) * 2048 + h * 256 + d] = f2b(a0);
    Wov3[(o0 + 1) * 2048 + h * 256 + d] = f2b(a1);
    Wov3[(o0 + 2) * 2048 + h * 256 + d] = f2b(a2);
    Wov3[(o0 + 3) * 2048 + h * 256 + d] = f2b(a3);
  } else if (blk < 1032) {
    int h = blk - 1024;
    float s1 = 0.f, s2 = 0.f;
    for (int dd = 0; dd < 256; ++dd) {
      s1 += bk[h * 256 + dd] * Wq[(h * 256 + dd) * 256 + t];
      s2 += bq[h * 256 + dd] * Wk[(h * 256 + dd) * 256 + t];
    }
    Aext[(2048 + h) * 256 + t] = f2b(s1);
    Aext[(2056 + h) * 256 + t] = f2b(s2);
  } else if (blk == 1032) {
    for (int i = t; i < 112 * 256 / 8; i += 256)
      *(u16x8*)(Aext + 2064 * 256 + i * 8) = (u16x8){0,0,0,0,0,0,0,0};
  } else if (blk < 1289) {
    int o = blk - 1033;
    const float* wob = Wo + o * 2048;
    float acc = 0.f;
#pragma unroll
    for (int j = 0; j < 8; ++j) acc += wob[j * 256 + t] * bv[j * 256 + t];
#pragma unroll
    for (int s = 1; s < 64; s <<= 1) acc += __shfl_xor(acc, s);
    if ((t & 63) == 0) red[t >> 6] = acc;
    __syncthreads();
    if (t == 0) cvec[o] = bo[o] + red[0] + red[1] + red[2] + red[3];
  } else {
    if (t < 8) {
      float c = 0.f;
      for (int dd = 0; dd < 256; ++dd) c += bk[t * 256 + dd] * bq[t * 256 + dd];
      red[t] = c * 0.0625f;
    }
    __syncthreads();
    for (int i = t; i < 8 * 169; i += 256) {
      int h = i / 169, idx = i - h * 169;
      relL2[i] = relc[idx * 8 + h] + red[h];
    }
  }
}

// ================= conv: rolled gather, coalesced bf16 stores =============
__global__ void k_conv(const float* __restrict__ X, ushort_t* __restrict__ Xroll) {
  const int n = blockIdx.x / 57, y = blockIdx.x % 57;
  ushort_t* xr = Xroll + (size_t)n * TROWS * 256;
  const int d = threadIdx.x;
  if (y == 56) {  // zero pad rows 3136..3199
    for (int i = d; i < 64 * 256 / 8; i += 256)
      *(u16x8*)(xr + 3136 * 256 + i * 8) = (u16x8){0,0,0,0,0,0,0,0};
    return;
  }
  const int c = d >> 4, p1 = (d >> 2) & 3, p2 = d & 3;
  const int sp = c * 16 + (((p1 + 1) & 3) << 2) + ((p2 + 1) & 3);
  const int ty = (p1 == 3) ? y : ((y == 0) ? 55 : y - 1);
  const float* rowp = X + (size_t)n * 256 * 3136 + sp * 3136 + ty * 56;
  ushort_t* orow = xr + y * 56 * 256 + d;
  for (int x = 0; x < 56; ++x) {
    int tx = (p2 == 3) ? x : ((x == 0) ? 55 : x - 1);
    orow[x * 256] = f2b(rowp[tx]);   // 256 lanes -> 512B contiguous store
  }
}

// ================= gemm1: M_T[t][a'] = Xroll . Aext^T =====================
// R9 persistent pipelined version. Block = (n = XCD, aa, chunk c of 7).
//   - Wave (wa=wave>>1, wt=wave&1) owns a-rows [a0+wa*64,+64) in regs
//     (areg[8][4] = 128 VGPR) x t-rows [tb+wt*32,+32).
//   - Per kk: 2 ds_read_b128 (B) feed 16 MFMAs (1:8 ratio; R8 was 1:2).
//   - t-loop: double-buffered 64x256 B-tile, raw s_barrier + COUNTED
//     vmcnt(16/8): fills stay in flight across barriers.
//   - 119 blocks/XCD = rounds of 64/55 (R8's 136 = 64/64/8 tail).
__global__ __launch_bounds__(256, 2) void k_gemm1(
    const ushort_t* __restrict__ Xroll, const ushort_t* __restrict__ Aext,
    ushort_t* __restrict__ MT) {
  __shared__ ushort_t Bsm[2][64 * 256];   // 2 x 32 KB
  const int bx0 = blockIdx.x;
  const int n = bx0 & 7;                  // XCD-bijective: XCD k owns batch k
  const int inner = bx0 >> 3;             // 0..118
  const int aa = inner % 17;
  const int c  = inner / 17;              // chunk 0..6
  const int a0 = aa * 128;
  const int tstart = (c == 0) ? 0 : (7 * c + 1);  // in 64-row tiles
  const int T = (c == 0) ? 8 : 7;                 // 8 + 6x7 = 50 tiles
  const int tid = threadIdx.x, wave = tid >> 6, lane = tid & 63;
  const int quad = lane >> 4, l16 = lane & 15;
  const int wa = wave >> 1, wt = wave & 1;
  const ushort_t* Xn = Xroll + (size_t)n * TROWS * 256;
  ushort_t* Mn = MT + (size_t)n * TROWS * MSTR;

  // ---- A-slice into regs: wave owns rows [a0+wa*64, +64), full K ----
  const ushort_t* abase = Aext + (size_t)(a0 + wa * 64 + l16) * 256 + quad * 8;
  bf16x8 areg[8][4];
#pragma unroll
  for (int kk = 0; kk < 8; ++kk)
#pragma unroll
    for (int i = 0; i < 4; ++i)
      areg[kk][i] = *(const bf16x8*)(abase + i * 4096 + kk * 32);   // 32 loads
  sb0();

  // ---- DMA fill of one 64x256 tile (swizzled), 8 insts/wave ----
  auto fill = [&](int mt, int b) {
    const ushort_t* src = Xn + (size_t)(tstart + mt) * 64 * 256;
#pragma unroll
    for (int i = 0; i < 8; ++i) {
      int S = i * 256 + tid;
      int rr = S >> 5, sc = S & 31;
      int cc = (sc & 24) | ((sc ^ rr) & 7);
      gload_lds16(src + rr * 256 + cc * 8, &Bsm[b][(i * 256 + wave * 64) * 8]);
    }
  };

  fill(0, 0); sb0();
  fill(1, 1); sb0();
  // outstanding: A(32), f0(8), f1(8). vmcnt(8) => A + f0 complete.
  asm volatile("s_waitcnt vmcnt(8)" ::: "memory"); sb0();
  __builtin_amdgcn_s_barrier(); sb0();

  const int sw = l16 & 7;
  for (int m = 0; m < T; ++m) {
    if (m > 0) {
      // need fill(m) done. Issued after it: stores(m-1)[8] (+ fill(m+1)[8]).
      if (m + 1 < T) { asm volatile("s_waitcnt vmcnt(16)" ::: "memory"); }
      else           { asm volatile("s_waitcnt vmcnt(8)"  ::: "memory"); }
      sb0();
      __builtin_amdgcn_s_barrier(); sb0();
    }
    const int b = m & 1;
    f32x4 acc[4][2];
#pragma unroll
    for (int i = 0; i < 4; ++i)
#pragma unroll
      for (int j = 0; j < 2; ++j) acc[i][j] = (f32x4){0.f, 0.f, 0.f, 0.f};
#pragma unroll
    for (int kk = 0; kk < 8; ++kk) {
      bf16x8 bfj[2];
#pragma unroll
      for (int j = 0; j < 2; ++j) {
        int rr = wt * 32 + j * 16 + l16;
        int cc = kk * 4 + quad;
        int pos = (cc & 24) | ((cc ^ sw) & 7);
        bfj[j] = *(const bf16x8*)(&Bsm[b][rr * 256 + pos * 8]);
      }
#pragma unroll
      for (int i = 0; i < 4; ++i)
#pragma unroll
        for (int j = 0; j < 2; ++j)
          acc[i][j] = __builtin_amdgcn_mfma_f32_16x16x32_bf16(areg[kk][i], bfj[j], acc[i][j], 0, 0, 0);
    }
    // stores: 8 per wave (counted in the vmcnt schedule)
    const int tb = (tstart + m) * 64;
#pragma unroll
    for (int i = 0; i < 4; ++i)
#pragma unroll
      for (int j = 0; j < 2; ++j) {
        int tg = tb + wt * 32 + j * 16 + l16;
        int ag = a0 + wa * 64 + i * 16 + quad * 4;
        *(ushort4*)(Mn + (size_t)tg * MSTR + ag) = pack4(acc[i][j]);
      }
    sb0();
    __builtin_amdgcn_s_barrier(); sb0();   // all waves done reading buf b
    if (m + 2 < T) { fill(m + 2, b); sb0(); }
  }
}

// ================= attn2 (unchanged) ==============================
#define XP_STR 264
__global__ __launch_bounds__(512, 4) void k_attn2(
    const ushort_t* __restrict__ Xroll, ushort_t* __restrict__ MT,
    const float* __restrict__ relL2) {
  __shared__ ushort_t Xp[64 * XP_STR];
  __shared__ ushort_t StB[2][64 * 72];
  __shared__ float aqsL[8 * 64];
  __shared__ float bpsL[8 * 64];
  __shared__ float relLh[8 * 169];

  const int tid = threadIdx.x;
  const int wave = tid >> 6, lane = tid & 63;
  const int quad = lane >> 4, l16 = lane & 15;
  const int group = wave >> 2, wv = wave & 3;
  const int n = blockIdx.x >> 6, g = blockIdx.x & 63;
  const int gi = g >> 3, gj = g & 7;
  const ushort_t* Xn = Xroll + (size_t)n * TROWS * 256;
  ushort_t* Mn = MT + (size_t)n * TROWS * MSTR;

  {
    const int p = tid & 63, cg = tid >> 6;
    if (p < 49) {
      int t = tmap(p, gi, gj);
#pragma unroll
      for (int i = 0; i < 4; ++i)
        *(u16x8*)(&Xp[p * XP_STR + (cg * 4 + i) * 8]) =
            *(const u16x8*)(Xn + t * 256 + (cg * 4 + i) * 8);
    } else {
#pragma unroll
      for (int i = 0; i < 4; ++i)
        *(u16x8*)(&Xp[p * XP_STR + (cg * 4 + i) * 8]) = (u16x8){0,0,0,0,0,0,0,0};
    }
  }
  for (int i = tid; i < 8 * 169; i += 512) relLh[i] = relL2[i];
  {
    const int h = tid >> 6, q = tid & 63;
    int qq = (q < 49) ? q : 48;
    int t = tmap(qq, gi, gj);
    aqsL[h * 64 + q] = b2f(Mn[(size_t)t * MSTR + 2048 + h]);
    bpsL[h * 64 + q] = b2f(Mn[(size_t)t * MSTR + 2056 + h]);
  }
  __syncthreads();

  bf16x8 xfr[4][2];
#pragma unroll
  for (int dt = 0; dt < 4; ++dt) {
    const int d = (wv * 4 + dt) * 16 + l16;
#pragma unroll
    for (int kk = 0; kk < 2; ++kk)
#pragma unroll
      for (int j = 0; j < 8; ++j)
        xfr[dt][kk][j] = (short)Xp[(kk * 32 + quad * 8 + j) * XP_STR + d];
  }

  const int q = wv * 16 + l16;
  const int qq = (q < 49) ? q : 48;
  const int tq = tmap(qq, gi, gj);
  const ushort_t* Mbase = Mn + (size_t)tq * MSTR + quad * 8;
  const int yq = div7(qq), xq = qq - yq * 7;
  const int fq = regof(gi * 7 + yq) * 3 + regof(gj * 7 + xq);

  for (int hh = 0; hh < 4; ++hh) {
    const int h = hh * 2 + group;
    f32x4 sacc[4];
#pragma unroll
    for (int pt = 0; pt < 4; ++pt) sacc[pt] = (f32x4){0.f, 0.f, 0.f, 0.f};
    const ushort_t* mrow = Mbase + h * 256;
#pragma unroll
    for (int kk = 0; kk < 8; ++kk) {
      bf16x8 bfm = *(const bf16x8*)(mrow + kk * 32);
#pragma unroll
      for (int pt = 0; pt < 4; ++pt) {
        bf16x8 af = *(const bf16x8*)(&Xp[(pt * 16 + l16) * XP_STR + kk * 32 + quad * 8]);
        sacc[pt] = __builtin_amdgcn_mfma_f32_16x16x32_bf16(af, bfm, sacc[pt], 0, 0, 0);
      }
    }
    float v[16];
    const float aqv = aqsL[h * 64 + q];
    const float* rel_h = &relLh[h * 169];
    float m = -1e30f;
#pragma unroll
    for (int pt = 0; pt < 4; ++pt)
#pragma unroll
      for (int r = 0; r < 4; ++r) {
        int p = pt * 16 + quad * 4 + r;
        float val = -1e30f;
        if (p < 49) {
          int yp = div7(p), xp = p - yp * 7;
          int fp = regof(gi * 7 + yp) * 3 + regof(gj * 7 + xp);
          val = (sacc[pt][r] + aqv + bpsL[h * 64 + p]) * 0.0625f +
                rel_h[(yp - yq + 6) + 13 * (xp - xq + 6)];
          if (fp != fq) val -= 100.f;
        }
        v[pt * 4 + r] = val;
        m = fmaxf(m, val);
      }
    m = fmaxf(m, __shfl_xor(m, 16));
    m = fmaxf(m, __shfl_xor(m, 32));
    float s = 0.f;
#pragma unroll
    for (int i = 0; i < 16; ++i) { v[i] = __expf(v[i] - m); s += v[i]; }
    s += __shfl_xor(s, 16);
    s += __shfl_xor(s, 32);
    const float inv = 1.f / s;
    __syncthreads();
    {
      ushort_t* sb = &StB[group][q * 72];
#pragma unroll
      for (int pt = 0; pt < 4; ++pt) {
        ushort4 u;
        u.x = f2b(v[pt * 4 + 0] * inv); u.y = f2b(v[pt * 4 + 1] * inv);
        u.z = f2b(v[pt * 4 + 2] * inv); u.w = f2b(v[pt * 4 + 3] * inv);
        *(ushort4*)(&sb[pt * 16 + quad * 4]) = u;
      }
    }
    __syncthreads();
#pragma unroll
    for (int qt = 0; qt < 4; ++qt) {
      f32x4 tacc[4];
#pragma unroll
      for (int dt = 0; dt < 4; ++dt) tacc[dt] = (f32x4){0.f, 0.f, 0.f, 0.f};
#pragma unroll
      for (int kk = 0; kk < 2; ++kk) {
        bf16x8 bfw = *(const bf16x8*)(&StB[group][(qt * 16 + l16) * 72 + kk * 32 + quad * 8]);
#pragma unroll
        for (int dt = 0; dt < 4; ++dt)
          tacc[dt] = __builtin_amdgcn_mfma_f32_16x16x32_bf16(xfr[dt][kk], bfw, tacc[dt], 0, 0, 0);
      }
      int q2 = qt * 16 + l16;
      if (q2 < 49) {
        int t2 = tmap(q2, gi, gj);
#pragma unroll
        for (int dt = 0; dt < 4; ++dt) {
          int d0 = (wv * 4 + dt) * 16 + quad * 4;
          *(ushort4*)(Mn + (size_t)t2 * MSTR + h * 256 + d0) = pack4(tacc[dt]);
        }
      }
    }
  }
}

// ================= gemm3: out[o][t] = Wov3 . T_T^T + cvec =================
// 128o x 128t tile, BK=128, 16 k-iters, DMA fills with XOR swizzle.
__global__ __launch_bounds__(256, 2) void k_gemm3(
    const ushort_t* __restrict__ Wov3, const ushort_t* __restrict__ MT,
    const float* __restrict__ cvec, float* __restrict__ out) {
  __shared__ ushort_t Asm[128 * 128];   // 32 KB
  __shared__ ushort_t Bsm[128 * 128];   // 32 KB
  const int bx0 = blockIdx.x;
  const int bx = (bx0 & 7) * 50 + (bx0 >> 3);    // bijective: 400 = 8*50
  const int n = bx / 50, r2 = bx % 50;
  const int oi = r2 / 25, tt = r2 % 25;
  const int o0 = oi * 128, t0 = tt * 128;
  const int tid = threadIdx.x, wave = tid >> 6, lane = tid & 63;
  const int quad = lane >> 4, l16 = lane & 15;
  const int wa = wave >> 1, wt = wave & 1;
  const ushort_t* Tn = MT + (size_t)n * TROWS * MSTR;
  float* on = out + (size_t)n * 256 * 3136;
  const int sw = l16 & 7;

  f32x4 acc[4][4];
#pragma unroll
  for (int i = 0; i < 4; ++i)
#pragma unroll
    for (int j = 0; j < 4; ++j) acc[i][j] = (f32x4){0.f, 0.f, 0.f, 0.f};

  for (int kit = 0; kit < 16; ++kit) {
    const int kb = kit * 128;
    // fill A[128][128] and B[128][128], 16B chunks, swizzle c^=(r&7)
#pragma unroll
    for (int i = 0; i < 8; ++i) {
      int S = i * 256 + tid;
      int rr = S >> 4, sc = S & 15;
      int c = (sc & 8) | ((sc ^ rr) & 7);
      gload_lds16(Wov3 + (o0 + rr) * 2048 + kb + c * 8,
                  &Asm[(i * 256 + wave * 64) * 8]);
    }
#pragma unroll
    for (int i = 0; i < 8; ++i) {
      int S = i * 256 + tid;
      int rr = S >> 4, sc = S & 15;
      int c = (sc & 8) | ((sc ^ rr) & 7);
      gload_lds16(Tn + (size_t)(t0 + rr) * MSTR + kb + c * 8,
                  &Bsm[(i * 256 + wave * 64) * 8]);
    }
    __syncthreads();
#pragma unroll
    for (int kk = 0; kk < 4; ++kk) {
      bf16x8 af[4], bf[4];
      const int c = kk * 4 + quad;
      const int pos = (c & 8) | ((c ^ sw) & 7);
#pragma unroll
      for (int i = 0; i < 4; ++i)
        af[i] = *(const bf16x8*)(&Asm[(wa * 64 + i * 16 + l16) * 128 + pos * 8]);
#pragma unroll
      for (int j = 0; j < 4; ++j)
        bf[j] = *(const bf16x8*)(&Bsm[(wt * 64 + j * 16 + l16) * 128 + pos * 8]);
#pragma unroll
      for (int i = 0; i < 4; ++i)
#pragma unroll
        for (int j = 0; j < 4; ++j)
          acc[i][j] = __builtin_amdgcn_mfma_f32_16x16x32_bf16(af[i], bf[j], acc[i][j], 0, 0, 0);
    }
    __syncthreads();
  }
  // epilogue: + cvec, guard pad tokens (regular stores -> L2 write-combining)
#pragma unroll
  for (int i = 0; i < 4; ++i) {
    const int ob = o0 + wa * 64 + i * 16 + quad * 4;
    const float4 cv = *(const float4*)(cvec + ob);
#pragma unroll
    for (int j = 0; j < 4; ++j) {
      const int tg = t0 + wt * 64 + j * 16 + l16;
      if (tg < 3136) {
        on[(size_t)(ob + 0) * 3136 + tg] = acc[i][j][0] + cv.x;
        on[(size_t)(ob + 1) * 3136 + tg] = acc[i][j][1] + cv.y;
        on[(size_t)(ob + 2) * 3136 + tg] = acc[i][j][2] + cv.z;
        on[(size_t)(ob + 3) * 3136 + tg] = acc[i][j][3] + cv.w;
      }
    }
  }
}

extern "C" void kernel_launch(void* const* d_in, const int* in_sizes, int n_in,
                              void* d_out, int out_size, void* d_ws, size_t ws_size,
                              hipStream_t stream) {
  (void)in_sizes; (void)n_in; (void)out_size; (void)ws_size;
  const float* X  = (const float*)d_in[0];
  const float* Wk = (const float*)d_in[1];
  const float* bk = (const float*)d_in[2];
  const float* Wq = (const float*)d_in[3];
  const float* bq = (const float*)d_in[4];
  const float* Wv = (const float*)d_in[5];
  const float* bv = (const float*)d_in[6];
  const float* Wo = (const float*)d_in[7];
  const float* bo = (const float*)d_in[8];
  const float* rc = (const float*)d_in[9];

  ushort_t* MT    = (ushort_t*)d_ws;                       // 8*3200*2176 u16
  ushort_t* Xroll = MT + (size_t)8 * TROWS * MSTR;         // 8*3200*256 u16
  ushort_t* Aext  = Xroll + (size_t)8 * TROWS * 256;       // 2176*256 u16
  ushort_t* Wov3  = Aext + 2176 * 256;                     // 256*2048 u16
  float* fbase = (float*)(Wov3 + 256 * 2048);
  float* cvec  = fbase;         // 256 f32
  float* relL2 = fbase + 256;   // 8*169 f32
  float* out = (float*)d_out;

  k_prep <<<dim3(1290), dim3(256), 0, stream>>>(Wk, Wq, Wo, Wv, bk, bq, bv, bo, rc,
                                                Aext, Wov3, cvec, relL2);
  k_conv <<<dim3(8 * 57), dim3(256), 0, stream>>>(X, Xroll);
  k_gemm1<<<dim3(8 * 119), dim3(256), 0, stream>>>(Xroll, Aext, MT);
  k_attn2<<<dim3(8 * 64), dim3(512), 0, stream>>>(Xroll, MT, relL2);
  k_gemm3<<<dim3(8 * 50), dim3(256), 0, stream>>>(Wov3, MT, cvec, out);
}